// Round 1
// baseline (110.675 us; speedup 1.0000x reference)
//
#include <hip/hip_runtime.h>
#include <hip/hip_bf16.h>

typedef __attribute__((ext_vector_type(8))) short short8;
typedef __attribute__((ext_vector_type(4))) float f32x4;

#define LN_EPS 1e-5f

__device__ __forceinline__ unsigned short bf16rn(float f) {
    unsigned int u = __builtin_bit_cast(unsigned int, f);
    u = u + 0x7fffu + ((u >> 16) & 1u);
    return (unsigned short)(u >> 16);
}

// ---------------- K0: W2 (128x2048 f32) -> bf16 ----------------
__global__ __launch_bounds__(256) void k_cvt_w2(const float* __restrict__ w2,
                                                unsigned short* __restrict__ o) {
    int i = (blockIdx.x * 256 + threadIdx.x) * 4;
    float4 v = *(const float4*)(w2 + i);
    ushort4 r;
    r.x = bf16rn(v.x); r.y = bf16rn(v.y); r.z = bf16rn(v.z); r.w = bf16rn(v.w);
    *(ushort4*)(o + i) = r;
}

// ---------------- K1: attn + LN1 -> x1 (=d_out), q ----------------
// One token per 16-lane group; lane li holds head li (8 features).
__global__ __launch_bounds__(256) void k_pre(const float* __restrict__ x,
                                             const float* __restrict__ theta,
                                             const float* __restrict__ phi,
                                             const float* __restrict__ gamma1,
                                             const float* __restrict__ beta1,
                                             float* __restrict__ x1,
                                             float* __restrict__ qv) {
    const int tid = threadIdx.x;
    const int g = tid >> 4, li = tid & 15;
    const int tok = blockIdx.x * 16 + g;

    const float* xr = x + (size_t)tok * 128 + li * 8;
    float4 va = *(const float4*)xr;
    float4 vb = *(const float4*)(xr + 4);
    float v[8] = {va.x, va.y, va.z, va.w, vb.x, vb.y, vb.z, vb.w};

    float c[8];
#pragma unroll
    for (int k = 0; k < 8; ++k) c[k] = __cosf(v[k] + theta[k]);
    float cp[8];
    cp[0] = c[0];
#pragma unroll
    for (int k = 1; k < 8; ++k) cp[k] = cp[k - 1] * c[k];

    float y[8];
    y[0] = v[0] + cp[7];  // wire 0 gets full product
#pragma unroll
    for (int k = 1; k < 8; ++k) y[k] = v[k] + cp[k];

    float s1 = 0.f, s2 = 0.f;
#pragma unroll
    for (int k = 0; k < 8; ++k) { s1 += y[k]; s2 += y[k] * y[k]; }
#pragma unroll
    for (int m = 1; m < 16; m <<= 1) {
        s1 += __shfl_xor(s1, m);
        s2 += __shfl_xor(s2, m);
    }
    float mean = s1 * (1.f / 128.f);
    float var = s2 * (1.f / 128.f) - mean * mean;
    float rs = rsqrtf(var + LN_EPS);

    float4 ga = *(const float4*)(gamma1 + li * 8);
    float4 gb = *(const float4*)(gamma1 + li * 8 + 4);
    float4 ba = *(const float4*)(beta1 + li * 8);
    float4 bb = *(const float4*)(beta1 + li * 8 + 4);
    float gam[8] = {ga.x, ga.y, ga.z, ga.w, gb.x, gb.y, gb.z, gb.w};
    float bet[8] = {ba.x, ba.y, ba.z, ba.w, bb.x, bb.y, bb.z, bb.w};

    float o[8];
#pragma unroll
    for (int k = 0; k < 8; ++k) o[k] = (y[k] - mean) * rs * gam[k] + bet[k];

    float* x1r = x1 + (size_t)tok * 128 + li * 8;
    *(float4*)x1r = make_float4(o[0], o[1], o[2], o[3]);
    *(float4*)(x1r + 4) = make_float4(o[4], o[5], o[6], o[7]);

    if (li == 0) {  // features 0..7 live in lane 0 of the group
        float* qr = qv + (size_t)tok * 8;
#pragma unroll
        for (int k = 0; k < 8; ++k) qr[k] = __cosf(phi[k]) * __cosf(o[k]);
    }
}

// ---------------- K2: fused FFN (8->2048->128) + residual + LN2 ----------------
// Block = 256 thr (4 waves). Wave handles 32 tokens = 2 MFMA M-tiles of 16.
// A-frag (h) computed in-register (fp32 exact, relu) and packed to bf16;
// B-frag = W2^T bf16 loaded from global (L2-resident, 512 KB).
// k-placement convention for BOTH operands: k = 8*(lane>>4) + j.
__global__ __launch_bounds__(256) void k_ffn(const float* __restrict__ x1,
                                             const float* __restrict__ qv,
                                             const unsigned short* __restrict__ w2b,
                                             const float* __restrict__ w1,
                                             const float* __restrict__ b1,
                                             const float* __restrict__ b2,
                                             const float* __restrict__ g2,
                                             const float* __restrict__ be2,
                                             float* __restrict__ out) {
    const int tid = threadIdx.x;
    const int wave = tid >> 6;
    const int lane = tid & 63;
    const int li = lane & 15;   // tile row (A) / col (B,C)
    const int lg = lane >> 4;   // k-group
    const int Tb = blockIdx.x * 128 + wave * 32;

    // q for my row in each of the 2 M-tiles
    float q0[8], q1[8];
    {
        const float* qp = qv + (size_t)(Tb + li) * 8;
        float4 a = *(const float4*)qp, b = *(const float4*)(qp + 4);
        q0[0] = a.x; q0[1] = a.y; q0[2] = a.z; q0[3] = a.w;
        q0[4] = b.x; q0[5] = b.y; q0[6] = b.z; q0[7] = b.w;
        const float* qp1 = qv + (size_t)(Tb + 16 + li) * 8;
        float4 a1 = *(const float4*)qp1, b1x = *(const float4*)(qp1 + 4);
        q1[0] = a1.x; q1[1] = a1.y; q1[2] = a1.z; q1[3] = a1.w;
        q1[4] = b1x.x; q1[5] = b1x.y; q1[6] = b1x.z; q1[7] = b1x.w;
    }

    f32x4 acc0[8], acc1[8];
#pragma unroll
    for (int nt = 0; nt < 8; ++nt) {
        acc0[nt] = f32x4{0.f, 0.f, 0.f, 0.f};
        acc1[nt] = f32x4{0.f, 0.f, 0.f, 0.f};
    }

    for (int step = 0; step < 64; ++step) {
        const int fb = step * 32 + lg * 8;

        // B fragments: 8 N-tiles, 8 contiguous bf16 each
        short8 bfr[8];
#pragma unroll
        for (int nt = 0; nt < 8; ++nt)
            bfr[nt] = *(const short8*)(w2b + (size_t)(nt * 16 + li) * 2048 + fb);

        // A fragments: h = relu(W1 q + b1), computed exactly in fp32
        short8 a0, a1;
#pragma unroll
        for (int j = 0; j < 8; ++j) {
            const int f = fb + j;
            const float* wr = w1 + f * 8;
            float4 wa = *(const float4*)wr;
            float4 wb = *(const float4*)(wr + 4);
            float bias = b1[f];
            float d0 = bias, d1 = bias;
            d0 = fmaf(wa.x, q0[0], d0); d0 = fmaf(wa.y, q0[1], d0);
            d0 = fmaf(wa.z, q0[2], d0); d0 = fmaf(wa.w, q0[3], d0);
            d0 = fmaf(wb.x, q0[4], d0); d0 = fmaf(wb.y, q0[5], d0);
            d0 = fmaf(wb.z, q0[6], d0); d0 = fmaf(wb.w, q0[7], d0);
            d1 = fmaf(wa.x, q1[0], d1); d1 = fmaf(wa.y, q1[1], d1);
            d1 = fmaf(wa.z, q1[2], d1); d1 = fmaf(wa.w, q1[3], d1);
            d1 = fmaf(wb.x, q1[4], d1); d1 = fmaf(wb.y, q1[5], d1);
            d1 = fmaf(wb.z, q1[6], d1); d1 = fmaf(wb.w, q1[7], d1);
            d0 = fmaxf(d0, 0.f);
            d1 = fmaxf(d1, 0.f);
            a0[j] = (short)bf16rn(d0);
            a1[j] = (short)bf16rn(d1);
        }

#pragma unroll
        for (int nt = 0; nt < 8; ++nt) {
            acc0[nt] = __builtin_amdgcn_mfma_f32_16x16x32_bf16(a0, bfr[nt], acc0[nt], 0, 0, 0);
            acc1[nt] = __builtin_amdgcn_mfma_f32_16x16x32_bf16(a1, bfr[nt], acc1[nt], 0, 0, 0);
        }
    }

    // epilogue: +b2, +x1 residual, LN2, store (C/D: col=lane&15, row=4*(lane>>4)+reg)
    float b2v[8], g2v[8], be2v[8];
#pragma unroll
    for (int nt = 0; nt < 8; ++nt) {
        int e = nt * 16 + li;
        b2v[nt] = b2[e]; g2v[nt] = g2[e]; be2v[nt] = be2[e];
    }

    auto epilogue = [&](const f32x4(&acc)[8], int mt) {
#pragma unroll
        for (int r = 0; r < 4; ++r) {
            const int trow = Tb + mt * 16 + lg * 4 + r;
            const float* x1r = x1 + (size_t)trow * 128;
            float vals[8];
            float s1 = 0.f, s2 = 0.f;
#pragma unroll
            for (int nt = 0; nt < 8; ++nt) {
                float vv = acc[nt][r] + b2v[nt] + x1r[nt * 16 + li];
                vals[nt] = vv;
                s1 += vv;
                s2 += vv * vv;
            }
#pragma unroll
            for (int m = 1; m < 16; m <<= 1) {
                s1 += __shfl_xor(s1, m);
                s2 += __shfl_xor(s2, m);
            }
            float mean = s1 * (1.f / 128.f);
            float var = s2 * (1.f / 128.f) - mean * mean;
            float rs = rsqrtf(var + LN_EPS);
            float* orow = out + (size_t)trow * 128;
#pragma unroll
            for (int nt = 0; nt < 8; ++nt)
                orow[nt * 16 + li] = (vals[nt] - mean) * rs * g2v[nt] + be2v[nt];
        }
    };
    epilogue(acc0, 0);
    epilogue(acc1, 1);
}

extern "C" void kernel_launch(void* const* d_in, const int* in_sizes, int n_in,
                              void* d_out, int out_size, void* d_ws, size_t ws_size,
                              hipStream_t stream) {
    const float* x      = (const float*)d_in[0];
    const float* theta  = (const float*)d_in[1];
    const float* phi    = (const float*)d_in[2];
    const float* w1     = (const float*)d_in[3];
    const float* b1     = (const float*)d_in[4];
    const float* w2     = (const float*)d_in[5];
    const float* b2     = (const float*)d_in[6];
    const float* gamma1 = (const float*)d_in[7];
    const float* beta1  = (const float*)d_in[8];
    const float* gamma2 = (const float*)d_in[9];
    const float* beta2  = (const float*)d_in[10];
    float* out = (float*)d_out;

    // x1 lives in d_out (same size); K2 reads it and overwrites in place.
    char* ws = (char*)d_ws;
    float* qv           = (float*)ws;                          // 32768*8*4 = 1 MB
    unsigned short* w2b = (unsigned short*)(ws + (1 << 20));   // 512 KB

    k_cvt_w2<<<256, 256, 0, stream>>>(w2, w2b);
    k_pre<<<2048, 256, 0, stream>>>(x, theta, phi, gamma1, beta1, out, qv);
    k_ffn<<<256, 256, 0, stream>>>(out, qv, w2b, w1, b1, b2, gamma2, beta2, out);
}